// Round 1
// baseline (182.656 us; speedup 1.0000x reference)
//
#include <hip/hip_runtime.h>

// Problem constants (from setup_inputs: B=2, C=512, H=128, W=256, G=8, maxdisp=48)
#define NB 2
#define NG 8
#define CG 64          // channels per group = 512/8
#define HH 128
#define WW 256
#define ND 48          // maxdisp
#define CHUNK 16       // c-chunk staged per iteration
#define TPB 192        // 3 waves: 6 d-tiles x 32 w-tiles
#define DT 8           // d per thread
#define WT 8           // w per thread
#define TGTW (WW + ND) // 304: tgt row padded with ND zeros on the left

__global__ __launch_bounds__(TPB, 3)
void gwc_kernel(const float* __restrict__ ref, const float* __restrict__ tgt,
                float* __restrict__ out) {
    __shared__ float sref[CHUNK][WW];    // 16 KB
    __shared__ float stgt[CHUNK][TGTW];  // 19.4 KB

    const int tid = threadIdx.x;
    const int blk = blockIdx.x;          // b*G*H + g*H + h  ->  (bg, h)
    const int h  = blk % HH;
    const int bg = blk / HH;             // b*8 + g; channel base = bg*64

    // Zero the left pad of stgt once; staging only writes columns [ND, TGTW).
    for (int i = tid; i < CHUNK * ND; i += TPB) {
        stgt[i / ND][i % ND] = 0.0f;
    }

    const int wt = tid & 31;             // w-tile 0..31
    const int dt = tid >> 5;             // d-tile 0..5
    const int w0 = wt * WT;              // 0..248
    const int d0 = dt * DT;              // 0..40

    float acc[DT][WT];
    #pragma unroll
    for (int i = 0; i < DT; ++i)
        #pragma unroll
        for (int j = 0; j < WT; ++j) acc[i][j] = 0.0f;

    const size_t rowstride = (size_t)HH * WW;                       // per-channel stride
    const float* refbase = ref + ((size_t)bg * CG * HH + h) * WW;   // (bg, c=0, h, 0)
    const float* tgtbase = tgt + ((size_t)bg * CG * HH + h) * WW;

    for (int ch = 0; ch < CG / CHUNK; ++ch) {
        __syncthreads();  // previous chunk's compute done before overwriting LDS
        // ---- stage CHUNK channels of ref and tgt (float4, coalesced) ----
        for (int i = tid; i < CHUNK * (WW / 4); i += TPB) {
            const int r = i >> 6;        // row within chunk (WW/4 = 64 float4 per row)
            const int q = i & 63;        // float4 index within row
            const float* gr = refbase + (size_t)(ch * CHUNK + r) * rowstride + q * 4;
            const float* gt = tgtbase + (size_t)(ch * CHUNK + r) * rowstride + q * 4;
            *(float4*)&sref[r][q * 4]      = *(const float4*)gr;
            *(float4*)&stgt[r][ND + q * 4] = *(const float4*)gt;
        }
        __syncthreads();
        // ---- accumulate over this chunk's channels ----
        #pragma unroll 2
        for (int c = 0; c < CHUNK; ++c) {
            float rv[WT];
            *(float4*)&rv[0] = *(const float4*)&sref[c][w0];
            *(float4*)&rv[4] = *(const float4*)&sref[c][w0 + 4];
            // tgt window: need stgt[c][ND + w0+ww - d0-dd] for ww in [0,8), dd in [0,8)
            // = indices [ND+w0-d0-7, ND+w0-d0+7]; a0 = ND+w0-d0-8 is a multiple of 8.
            float tv[16];
            const int a0 = ND + w0 - d0 - 8;
            #pragma unroll
            for (int k = 0; k < 4; ++k)
                *(float4*)&tv[k * 4] = *(const float4*)&stgt[c][a0 + k * 4];
            #pragma unroll
            for (int dd = 0; dd < DT; ++dd)
                #pragma unroll
                for (int ww = 0; ww < WT; ++ww)
                    acc[dd][ww] += rv[ww] * tv[8 + ww - dd];   // static idx in [1,15]
        }
    }

    // ---- epilogue: out[((bg*ND + d)*HH + h)*WW + w] ----
    float* obase = out + ((size_t)bg * ND + 0) * rowstride + (size_t)h * WW;
    #pragma unroll
    for (int dd = 0; dd < DT; ++dd) {
        float* orow = obase + (size_t)(d0 + dd) * rowstride + w0;
        *(float4*)&orow[0] = make_float4(acc[dd][0], acc[dd][1], acc[dd][2], acc[dd][3]);
        *(float4*)&orow[4] = make_float4(acc[dd][4], acc[dd][5], acc[dd][6], acc[dd][7]);
    }
}

extern "C" void kernel_launch(void* const* d_in, const int* in_sizes, int n_in,
                              void* d_out, int out_size, void* d_ws, size_t ws_size,
                              hipStream_t stream) {
    const float* ref = (const float*)d_in[0];
    const float* tgt = (const float*)d_in[1];
    float* out = (float*)d_out;
    const int grid = NB * NG * HH;   // 2048 blocks, one per (b, g, h)
    gwc_kernel<<<dim3(grid), dim3(TPB), 0, stream>>>(ref, tgt, out);
}

// Round 2
// 137.142 us; speedup vs baseline: 1.3319x; 1.3319x over previous
//
#include <hip/hip_runtime.h>

// Problem constants (B=2, C=512, H=128, W=256, G=8, maxdisp=48)
#define NB 2
#define NG 8
#define CG 64          // channels per group
#define HH 128
#define WW 256
#define ND 48          // maxdisp
#define CHUNK 8        // c-chunk staged per iteration (17.9 KB LDS -> 8 blocks/CU)
#define TPB 192        // 3 waves: 6 d-tiles x 32 w-tiles
#define DT 8           // d per thread
#define TGTW (WW + ND) // 304: tgt row left-padded with ND zeros

// Thread (wt, dt) owns w in {4wt..4wt+3} U {128+4wt..131+4wt}, d in {8dt..8dt+7}.
// All inner-loop ds_read_b128 are lane-contiguous (16B lane stride) -> conflict-free.

__global__ __launch_bounds__(TPB, 4)
void gwc_kernel(const float* __restrict__ ref, const float* __restrict__ tgt,
                float* __restrict__ out) {
    __shared__ float sref[CHUNK][WW];    // 8 KB
    __shared__ float stgt[CHUNK][TGTW];  // 9.5 KB

    const int tid = threadIdx.x;
    const int blk = blockIdx.x;          // b*G*H + g*H + h
    const int hrow = blk % HH;
    const int bg   = blk / HH;           // b*8 + g

    // Zero the left pad once; staging only writes columns [ND, TGTW).
    for (int i = tid; i < CHUNK * ND; i += TPB)
        stgt[i / ND][i % ND] = 0.0f;

    const int wt = tid & 31;             // w-tile 0..31
    const int dt = tid >> 5;             // d-tile 0..5
    const int d0 = dt * DT;              // 0,8,...,40

    float acc[2][DT][4];
    #pragma unroll
    for (int hf = 0; hf < 2; ++hf)
        #pragma unroll
        for (int i = 0; i < DT; ++i)
            #pragma unroll
            for (int j = 0; j < 4; ++j) acc[hf][i][j] = 0.0f;

    const size_t rowstride = (size_t)HH * WW;
    const float* refbase = ref + ((size_t)bg * CG * HH + hrow) * WW;
    const float* tgtbase = tgt + ((size_t)bg * CG * HH + hrow) * WW;

    for (int ch = 0; ch < CG / CHUNK; ++ch) {
        __syncthreads();  // previous chunk's compute done before overwrite
        // ---- stage CHUNK channels of ref and tgt (float4, coalesced) ----
        for (int i = tid; i < CHUNK * (WW / 4); i += TPB) {
            const int r = i >> 6;        // row in chunk (64 float4 per row)
            const int q = i & 63;        // float4 index within row
            const float* gr = refbase + (size_t)(ch * CHUNK + r) * rowstride + q * 4;
            const float* gt = tgtbase + (size_t)(ch * CHUNK + r) * rowstride + q * 4;
            *(float4*)&sref[r][q * 4]      = *(const float4*)gr;
            *(float4*)&stgt[r][ND + q * 4] = *(const float4*)gt;
        }
        __syncthreads();
        // ---- accumulate over this chunk's channels ----
        #pragma unroll 2
        for (int c = 0; c < CHUNK; ++c) {
            #pragma unroll
            for (int hf = 0; hf < 2; ++hf) {
                const int off = hf * 128;
                float rv[4];
                *(float4*)&rv[0] = *(const float4*)&sref[c][off + 4 * wt];
                // window: stgt[c][ND + (off+4wt+ww) - (d0+dd)], ww in [0,4), dd in [0,8)
                // col range = [a0+1, a0+11], a0 = ND-8 + off + 4wt - d0 (multiple of 4)
                float tv[12];
                const int a0 = (ND - 8) + off + 4 * wt - d0;
                #pragma unroll
                for (int k = 0; k < 3; ++k)
                    *(float4*)&tv[k * 4] = *(const float4*)&stgt[c][a0 + k * 4];
                #pragma unroll
                for (int dd = 0; dd < DT; ++dd)
                    #pragma unroll
                    for (int ww = 0; ww < 4; ++ww)
                        acc[hf][dd][ww] += rv[ww] * tv[8 + ww - dd];  // static idx in [1,11]
            }
        }
    }

    // ---- epilogue: out[((bg*ND + d)*HH + hrow)*WW + w] ----
    float* obase = out + ((size_t)bg * ND) * rowstride + (size_t)hrow * WW;
    #pragma unroll
    for (int hf = 0; hf < 2; ++hf) {
        const int off = hf * 128;
        #pragma unroll
        for (int dd = 0; dd < DT; ++dd) {
            float* orow = obase + (size_t)(d0 + dd) * rowstride + off + 4 * wt;
            *(float4*)orow = make_float4(acc[hf][dd][0], acc[hf][dd][1],
                                         acc[hf][dd][2], acc[hf][dd][3]);
        }
    }
}

extern "C" void kernel_launch(void* const* d_in, const int* in_sizes, int n_in,
                              void* d_out, int out_size, void* d_ws, size_t ws_size,
                              hipStream_t stream) {
    const float* ref = (const float*)d_in[0];
    const float* tgt = (const float*)d_in[1];
    float* out = (float*)d_out;
    const int grid = NB * NG * HH;   // 2048 blocks, one per (b, g, h)
    gwc_kernel<<<dim3(grid), dim3(TPB), 0, stream>>>(ref, tgt, out);
}

// Round 3
// 108.168 us; speedup vs baseline: 1.6886x; 1.2679x over previous
//
#include <hip/hip_runtime.h>

// Problem constants (B=2, C=512, H=128, W=256, G=8, maxdisp=48)
#define NB 2
#define NG 8
#define CG 64          // channels per group
#define HH 128
#define WW 256
#define ND 48          // maxdisp
#define CHUNK 8        // c-chunk staged per iteration (17.9 KB LDS)
#define TPB 192        // 3 waves: 6 d-tiles x 32 w-tiles
#define DT 8           // d per thread
#define TGTW (WW + ND) // 304 floats = 76 float4 slots per row

// XOR swizzle on float4-slot index: involution within aligned 4-slot blocks.
// Breaks the 4-way pass conflict of 16B-lane-stride ds_read_b128/ds_write_b128
// (lanes i, i+8, i+16, i+24 shared a bank quad; now they hit g, g^1, g^2, g^3).
__device__ __forceinline__ int swz(int q) { return q ^ ((q >> 3) & 3); }

__global__ __launch_bounds__(TPB, 4)
void gwc_kernel(const float* __restrict__ ref, const float* __restrict__ tgt,
                float* __restrict__ out) {
    __shared__ float sref[CHUNK][WW];    // 8 KB,  64 float4 slots/row
    __shared__ float stgt[CHUNK][TGTW];  // 9.5 KB, 76 float4 slots/row (slots 0..11 = zero pad)

    const int tid = threadIdx.x;
    const int blk = blockIdx.x;          // b*G*H + g*H + h
    const int hrow = blk % HH;
    const int bg   = blk / HH;           // b*8 + g

    // Zero the pad (physical slots 0..11 per row; swizzle maps pads onto pads).
    for (int i = tid; i < CHUNK * ND; i += TPB)
        stgt[i / ND][i % ND] = 0.0f;

    const int wt = tid & 31;             // w-tile 0..31
    const int dt = tid >> 5;             // d-tile 0..5
    const int d0 = dt * DT;

    // Precomputed swizzled float offsets (c-independent; inner loop adds c via imm offset).
    const int qr0 = 4 * swz(wt);         // rv base, hf=0 (logical slot wt)
    const int qr1 = 4 * swz(32 + wt);    // rv base, hf=1
    int qt[2][3];
    #pragma unroll
    for (int hf = 0; hf < 2; ++hf)
        #pragma unroll
        for (int k = 0; k < 3; ++k) {
            const int q = 10 + 32 * hf + wt - 2 * dt + k;  // logical slot in [0,76)
            qt[hf][k] = 4 * swz(q);
        }

    float acc[2][DT][4];
    #pragma unroll
    for (int hf = 0; hf < 2; ++hf)
        #pragma unroll
        for (int i = 0; i < DT; ++i)
            #pragma unroll
            for (int j = 0; j < 4; ++j) acc[hf][i][j] = 0.0f;

    const size_t rowstride = (size_t)HH * WW;
    const float* refbase = ref + ((size_t)bg * CG * HH + hrow) * WW;
    const float* tgtbase = tgt + ((size_t)bg * CG * HH + hrow) * WW;

    for (int ch = 0; ch < CG / CHUNK; ++ch) {
        __syncthreads();  // previous chunk's reads done before overwrite
        // ---- stage CHUNK channels (global reads coalesced; LDS writes swizzled) ----
        for (int i = tid; i < CHUNK * 64; i += TPB) {
            const int r = i >> 6;        // row in chunk
            const int q = i & 63;        // logical float4 slot
            const float* gr = refbase + (size_t)(ch * CHUNK + r) * rowstride + q * 4;
            const float* gt = tgtbase + (size_t)(ch * CHUNK + r) * rowstride + q * 4;
            *(float4*)&sref[r][4 * swz(q)]      = *(const float4*)gr;
            *(float4*)&stgt[r][4 * swz(q + 12)] = *(const float4*)gt;  // logical slot q+12
        }
        __syncthreads();
        // ---- accumulate over this chunk's channels ----
        #pragma unroll
        for (int c = 0; c < CHUNK; ++c) {
            #pragma unroll
            for (int hf = 0; hf < 2; ++hf) {
                float rv[4];
                *(float4*)&rv[0] = *(const float4*)&sref[c][hf ? qr1 : qr0];
                float tv[12];
                #pragma unroll
                for (int k = 0; k < 3; ++k)
                    *(float4*)&tv[k * 4] = *(const float4*)&stgt[c][qt[hf][k]];
                #pragma unroll
                for (int dd = 0; dd < DT; ++dd)
                    #pragma unroll
                    for (int ww = 0; ww < 4; ++ww)
                        acc[hf][dd][ww] += rv[ww] * tv[8 + ww - dd];  // static idx in [1,11]
            }
        }
    }

    // ---- epilogue: out[((bg*ND + d)*HH + hrow)*WW + w] ----
    float* obase = out + ((size_t)bg * ND) * rowstride + (size_t)hrow * WW;
    #pragma unroll
    for (int hf = 0; hf < 2; ++hf) {
        const int off = hf * 128;
        #pragma unroll
        for (int dd = 0; dd < DT; ++dd) {
            float* orow = obase + (size_t)(d0 + dd) * rowstride + off + 4 * wt;
            *(float4*)orow = make_float4(acc[hf][dd][0], acc[hf][dd][1],
                                         acc[hf][dd][2], acc[hf][dd][3]);
        }
    }
}

extern "C" void kernel_launch(void* const* d_in, const int* in_sizes, int n_in,
                              void* d_out, int out_size, void* d_ws, size_t ws_size,
                              hipStream_t stream) {
    const float* ref = (const float*)d_in[0];
    const float* tgt = (const float*)d_in[1];
    float* out = (float*)d_out;
    const int grid = NB * NG * HH;   // 2048 blocks, one per (b, g, h)
    gwc_kernel<<<dim3(grid), dim3(TPB), 0, stream>>>(ref, tgt, out);
}

// Round 4
// 107.481 us; speedup vs baseline: 1.6994x; 1.0064x over previous
//
#include <hip/hip_runtime.h>

// Problem constants (B=2, C=512, H=128, W=256, G=8, maxdisp=48)
#define NB 2
#define NG 8
#define CG 64          // channels per group
#define HH 128
#define WW 256
#define ND 48          // maxdisp
#define CHUNK 8        // c-chunk staged per iteration (17.9 KB LDS)
#define TPB 192        // 3 waves; wave wv owns d in [16wv, 16wv+16)
#define DT 16          // d per thread
#define TGTW (WW + ND) // 304 floats = 76 float4 slots/row (slots 0..11 = zero pad)

// Full 3-bit XOR swizzle on float4-slot index. Involution within aligned
// 8-slot (128B) blocks -> in-bounds, pad-preserving. Makes both slot-stride-1
// and slot-stride-8 lane patterns hit 8 distinct bank-quads per pass group.
__device__ __forceinline__ int swz8(int q) { return q ^ ((q >> 3) & 7); }

__global__ __launch_bounds__(TPB, 4)
void gwc_kernel(const float* __restrict__ ref, const float* __restrict__ tgt,
                float* __restrict__ out) {
    __shared__ float sref[CHUNK][WW];    // 8 KB,  64 slots/row
    __shared__ float stgt[CHUNK][TGTW];  // 9.5 KB, 76 slots/row

    const int tid  = threadIdx.x;
    const int lane = tid & 63;
    const int wv   = tid >> 6;           // 0..2 -> d0 = 16*wv
    const int d0   = DT * wv;

    const int blk = blockIdx.x;          // b*G*H + g*H + h
    const int hrow = blk % HH;
    const int bg   = blk / HH;

    // Zero the left pad (logical slots 0..11; swz8 maps pad slots onto pad slots).
    for (int i = tid; i < CHUNK * ND; i += TPB)
        stgt[i / ND][i % ND] = 0.0f;

    // Per-thread swizzled read offsets (floats; c enters via row base, const-folded).
    const int roff = 4 * swz8(lane);     // rv: logical slot = lane
    int toff[5];
    #pragma unroll
    for (int k = 0; k < 5; ++k)
        toff[k] = 4 * swz8((8 - 4 * wv) + lane + k);   // slots in [0, 76)

    float acc[DT][4];
    #pragma unroll
    for (int i = 0; i < DT; ++i)
        #pragma unroll
        for (int j = 0; j < 4; ++j) acc[i][j] = 0.0f;

    const size_t rowstride = (size_t)HH * WW;
    const float* refbase = ref + ((size_t)bg * CG * HH + hrow) * WW;
    const float* tgtbase = tgt + ((size_t)bg * CG * HH + hrow) * WW;

    for (int ch = 0; ch < CG / CHUNK; ++ch) {
        __syncthreads();  // previous chunk's reads done before overwrite
        // ---- stage CHUNK channels (coalesced global float4; swizzled LDS writes) ----
        for (int i = tid; i < CHUNK * 64; i += TPB) {
            const int r = i >> 6;        // row in chunk
            const int q = i & 63;        // logical float4 slot
            const float* gr = refbase + (size_t)(ch * CHUNK + r) * rowstride + q * 4;
            const float* gt = tgtbase + (size_t)(ch * CHUNK + r) * rowstride + q * 4;
            *(float4*)&sref[r][4 * swz8(q)]      = *(const float4*)gr;
            *(float4*)&stgt[r][4 * swz8(q + 12)] = *(const float4*)gt;
        }
        __syncthreads();
        // ---- accumulate ----
        #pragma unroll
        for (int c = 0; c < CHUNK; ++c) {
            float rv[4];
            *(float4*)&rv[0] = *(const float4*)&sref[c][roff];
            // tv window: floats [4*lane - d0 + 33, 4*lane - d0 + 51] (19 used of 20)
            float tv[20];
            #pragma unroll
            for (int k = 0; k < 5; ++k)
                *(float4*)&tv[k * 4] = *(const float4*)&stgt[c][toff[k]];
            #pragma unroll
            for (int dd = 0; dd < DT; ++dd)
                #pragma unroll
                for (int ww = 0; ww < 4; ++ww)
                    acc[dd][ww] += rv[ww] * tv[16 + ww - dd];  // static idx in [1,19]
        }
    }

    // ---- epilogue: out[((bg*ND + d)*HH + hrow)*WW + w], w = 4*lane ----
    float* obase = out + ((size_t)bg * ND) * rowstride + (size_t)hrow * WW + 4 * lane;
    #pragma unroll
    for (int dd = 0; dd < DT; ++dd) {
        float* orow = obase + (size_t)(d0 + dd) * rowstride;
        *(float4*)orow = make_float4(acc[dd][0], acc[dd][1], acc[dd][2], acc[dd][3]);
    }
}

extern "C" void kernel_launch(void* const* d_in, const int* in_sizes, int n_in,
                              void* d_out, int out_size, void* d_ws, size_t ws_size,
                              hipStream_t stream) {
    const float* ref = (const float*)d_in[0];
    const float* tgt = (const float*)d_in[1];
    float* out = (float*)d_out;
    const int grid = NB * NG * HH;   // 2048 blocks, one per (b, g, h)
    gwc_kernel<<<dim3(grid), dim3(TPB), 0, stream>>>(ref, tgt, out);
}